// Round 8
// baseline (280.474 us; speedup 1.0000x reference)
//
#include <hip/hip_runtime.h>
#include <hip/hip_bf16.h>
#include <stdint.h>

// Problem constants (fixed by setup_inputs)
#define FCB 2            // codebooks
#define BB 16            // batch
#define NN 256           // tokens per (b)
#define EDIM 1024
#define CC 512           // channels per codebook
#define NE 4096          // prototypes per codebook
#define TOKENS (BB*FCB*NN)   // 8192
#define ROWS (FCB*NE)        // 8192 emb rows
#define OUT_LOSS (BB*NN*EDIM)   // 4194304 (also the element count for the mean)
#define OUT_IDX  (OUT_LOSS + 1)
#define MARGIN 0.15f     // rescore margin, v-units (v = z.e/||e|| ~ 22.6*cos); ~24 sigma of bf16 noise

typedef __attribute__((ext_vector_type(8))) short bf16x8;   // MFMA A/B frag (4 VGPRs)
typedef __attribute__((ext_vector_type(4))) float f32x4;    // 16x16 MFMA C/D frag

// monotonic float<->uint mapping for packed argmax
__device__ __forceinline__ unsigned int ford(float v) {
    unsigned int u = __float_as_uint(v);
    return (u & 0x80000000u) ? ~u : (u | 0x80000000u);
}
__device__ __forceinline__ float unford(unsigned int u) {
    unsigned int b = (u & 0x80000000u) ? (u & 0x7fffffffu) : ~u;
    return __uint_as_float(b);
}

// ---------------------------------------------------------------------------
// ws layout:
//   [0]        norm_sq   8192 f32                   (32 KB)  written once by pack_hi (no atomics)
//   [32768]    cand      8192 tok x 64 slots x 2 u32 (4 MB)  top-2 per 64-col group
//   [32768+4M] loss_tok  8192 f32                   (32 KB)
//   [+32KB]    z_hi      2*4096*512 bf16            (8 MB)   fragment-packed
//   [+8MB]     e_hi      2*4096*512 bf16            (8 MB)
// Packed layout: elem = ((f*256 + R)*64 + Q)*128 + m*8 + j
//   (R = 16-row tile, Q = 8-elem k-chunk, m = row-in-tile, j = elem).
//   One 1-KB staging chunk = (R, qb..qb+3) = 16 rows x 32 k; both the
//   global_load_lds staging and ds_read_b128 fragment reads are lane-linear
//   (lane <-> 16 B), conflict-free.
//
// Session ledger (what's proven on this problem):
//   gemm: duration fits dur ~= 30 + 64/(blocks-per-CU) us -- per-step
//         stage-drain latency amortized by co-resident overlap.  1 blk/CU
//         (R1, deep pipeline) = 92us; 2 (R3 dbuf) = 60; ~2.65 (R0) = 52.
//         XCD remap (R4): 3x FETCH, no change -> NOT delivery-BW-bound.
//         Pointer hoist (R5): +16 VGPR, lost 3us.  This round: more waves
//         per step (8-wave 256x128 tile), same 2-barrier structure.
//   cross-block serialization (single-address atomic R2, threadfence+counter
//         R6) costs 60-70us.  Keep loss_reduce as its own 3us kernel.
// ---------------------------------------------------------------------------

// ---- pack: fp32 -> bf16 hi, fragment-packed.  512-thread blocks, 1024 total.
// z half (blocks 0..511): 8 token rows via LDS transpose -> coalesced fp32
//   reads AND lane-linear packed stores (single ds_write_b64 per 4 elems).
// emb half (blocks 512..1023): block owns a full (f,R) 16-row tile (512 k),
//   per-row exact f32 norm^2 reduced in-block, plain store (no atomics).
__global__ __launch_bounds__(512) void pack_hi(
    const float* __restrict__ z, const float* __restrict__ emb,
    short* __restrict__ z_hi, short* __restrict__ e_hi,
    float* __restrict__ norm_sq)
{
    int bid = blockIdx.x;
    int tid = threadIdx.x;
    if (bid < 512) {
        // ---- z: 8 rows x 1024 cols, LDS-transposed ----
        __shared__ short lds[8][1032];              // 2064B rows: 16B-aligned
        int row0 = bid * 8;                         // token row base
        #pragma unroll
        for (int it = 0; it < 4; ++it) {
            int flat = it * 512 + tid;              // [0,2048) float4 units
            int row = flat >> 8;                    // 256 float4 per row
            int col4 = flat & 255;
            float4 v = *(const float4*)(z + ((size_t)(row0 + row)) * EDIM + col4 * 4);
            unsigned short s0, s1, s2, s3;
            { __hip_bfloat16 h = __float2bfloat16(v.x); s0 = *(unsigned short*)&h; }
            { __hip_bfloat16 h = __float2bfloat16(v.y); s1 = *(unsigned short*)&h; }
            { __hip_bfloat16 h = __float2bfloat16(v.z); s2 = *(unsigned short*)&h; }
            { __hip_bfloat16 h = __float2bfloat16(v.w); s3 = *(unsigned short*)&h; }
            uint2 pk;
            pk.x = (unsigned)s0 | ((unsigned)s1 << 16);
            pk.y = (unsigned)s2 | ((unsigned)s3 << 16);
            *(uint2*)&lds[row][col4 * 4] = pk;      // one ds_write_b64
        }
        __syncthreads();
        int R = bid >> 1, mb = (bid & 1) * 8;       // 16-row group, m base
        int ml = tid & 7;
        int Q  = tid >> 3;                          // [0,64)
        #pragma unroll
        for (int f = 0; f < 2; ++f) {
            bf16x8 h8 = *(const bf16x8*)&lds[ml][f * 512 + Q * 8];
            size_t u = ((size_t)((f * 256 + R) * 64 + Q)) * 16 + mb + ml;
            *(bf16x8*)(z_hi + u * 8) = h8;          // lane-linear 16 B stores
        }
    } else {
        // ---- emb: block owns (f, R): 16 rows x 512 k; 2 chunk-units/thread
        __shared__ float red[512];
        int e = bid - 512;                          // [0,512)
        int f = e >> 8, R = e & 255;
        int m = tid & 15;                           // same row for both units
        float ss = 0.f;
        #pragma unroll
        for (int i = 0; i < 2; ++i) {
            int ul = tid + 512 * i;                 // [0,1024)
            int Q = (ul >> 4) & 63;
            const float* s = emb + ((size_t)(f * NE + R * 16 + m)) * CC + Q * 8;
            float4 v0 = *(const float4*)s;
            float4 v1 = *(const float4*)(s + 4);
            float vv[8] = {v0.x, v0.y, v0.z, v0.w, v1.x, v1.y, v1.z, v1.w};
            bf16x8 h8;
            #pragma unroll
            for (int j = 0; j < 8; ++j) {
                __hip_bfloat16 hb = __float2bfloat16(vv[j]);
                h8[j] = *(short*)&hb;
                ss = fmaf(vv[j], vv[j], ss);
            }
            int u = ((f * 256 + R) * 64 + Q) * 16 + m;
            *(bf16x8*)(e_hi + (size_t)u * 8) = h8;
        }
        red[tid] = ss;
        __syncthreads();
        if (tid < 16) {
            float t = 0.f;
            #pragma unroll
            for (int q = 0; q < 32; ++q) t += red[tid + 16 * q];
            norm_sq[f * NE + R * 16 + tid] = t;     // exact f32, no atomic
        }
    }
}

// ---------------------------------------------------------------------------
// 256x128 bf16 MFMA GEMM (BK=64) + top-2 select -- R0's proven 2-barrier
// schedule, widened to 8 waves (4M x 2N; wave = 64x64 = acc[4][4], same
// per-wave footprint as R0).  48 KB LDS -> 3 blocks/CU = 24 waves/CU (vs
// R0's ~10.6): per-step useful work per CU doubles against the same stage
// drain, and per-CU sequential step-slots halve (4 blocks x 8 steps).
// Staged traffic drops 512 -> 384 MB.  Staging chunks: 48 x 1 KB, 6/wave.
// ---------------------------------------------------------------------------
__global__ __launch_bounds__(512, 6) void gemm_sel(
    const short* __restrict__ zh, const short* __restrict__ eh,
    const float* __restrict__ norm_sq, unsigned int* __restrict__ cand)
{
    __shared__ char smem[49152];      // A 32K (chunks 0..31) | B 16K (32..47)
    const int f  = blockIdx.z;
    const int t0 = blockIdx.y * 256;  // token base within codebook
    const int m0 = blockIdx.x * 128;  // proto base within codebook
    const int tid  = threadIdx.x;
    const int wave = tid >> 6, lane = tid & 63;
    const int wm = wave & 3, wn = wave >> 2;   // 4 M-waves x 2 N-waves

    f32x4 acc[4][4] = {};

    for (int step = 0; step < 8; ++step) {
        __syncthreads();              // previous compute done before overwrite
        // 48 chunks of 1 KB per step: A (c<32), B (c>=32); wave stages 6
        #pragma unroll
        for (int i = 0; i < 6; ++i) {
            int c = wave * 6 + i;
            bool isA = (c < 32);
            const short* gsrc = isA ? zh : eh;
            int cl = isA ? c : (c - 32);
            int Rl = cl >> 1, h = cl & 1;
            int R = (isA ? (t0 >> 4) : (m0 >> 4)) + Rl;
            int qb = step * 8 + h * 4;
            const short* g = gsrc
                + (((size_t)f * 256 + R) * 64 + qb) * 128 + (size_t)lane * 8;
            __builtin_amdgcn_global_load_lds(
                (const __attribute__((address_space(1))) void*)g,
                (__attribute__((address_space(3))) void*)(smem + c * 1024),
                16, 0, 0);
        }
        __syncthreads();              // staged data visible to all waves

        #pragma unroll
        for (int h = 0; h < 2; ++h) {
            bf16x8 ah[4], bh[4];
            #pragma unroll
            for (int i = 0; i < 4; ++i) {
                ah[i] = *(const bf16x8*)(smem + ((wm*4 + i)*2 + h) * 1024 + lane * 16);
                bh[i] = *(const bf16x8*)(smem + 32768 + ((wn*4 + i)*2 + h) * 1024 + lane * 16);
            }
            #pragma unroll
            for (int i = 0; i < 4; ++i)
                #pragma unroll
                for (int j2 = 0; j2 < 4; ++j2)
                    acc[i][j2] = __builtin_amdgcn_mfma_f32_16x16x32_bf16(ah[i], bh[j2], acc[i][j2], 0, 0, 0);
        }
    }

    // ---- selection epilogue: per token, top-2 over this wave's 64 cols ----
    // C/D layout (16x16x32): col = lane&15, row = (lane>>4)*4 + reg
    // u32 pack: score high bits | (col_local ^ 63)  (tie -> lower col wins;
    // truncation error <= 2e-4 absorbed by MARGIN; exact rescore follows)
    float inm[4]; unsigned ccode[4];
    #pragma unroll
    for (int j2 = 0; j2 < 4; ++j2) {
        int col = j2 * 16 + (lane & 15);              // [0,64) within wave group
        ccode[j2] = (unsigned)(col ^ 63);
        inm[j2] = rsqrtf(norm_sq[f * NE + m0 + wn * 64 + col]);
    }

    #pragma unroll
    for (int i = 0; i < 4; ++i) {
        #pragma unroll
        for (int r = 0; r < 4; ++r) {
            unsigned p1 = 0u, p2 = 0u;
            #pragma unroll
            for (int j2 = 0; j2 < 4; ++j2) {
                float w = acc[i][j2][r] * inm[j2];
                unsigned pw = (ford(w) & 0xFFFFFFC0u) | ccode[j2];
                if (pw > p1) { p2 = p1; p1 = pw; }
                else if (pw > p2) p2 = pw;
            }
            // merge top-2 across the 16 contiguous lanes of this token row
            #pragma unroll
            for (int off = 8; off; off >>= 1) {
                unsigned q1 = __shfl_down(p1, off, 16);
                unsigned q2 = __shfl_down(p2, off, 16);
                if (q1 > p1) { unsigned t = p1; p1 = q1; p2 = (t > q2) ? t : q2; }
                else         { p2 = (p2 > q1) ? p2 : q1; }
            }
            if ((lane & 15) == 0) {
                int u = t0 + wm * 64 + i * 16 + (lane >> 4) * 4 + r;
                int b = u >> 8, n = u & 255;
                int gt = ((b * FCB + f) << 8) + n;   // global token id (b,f,n)
                int s = (blockIdx.x << 1) | wn;      // slot covers cols s*64..
                uint2 val; val.x = p1; val.y = p2;
                *(uint2*)(cand + ((size_t)gt << 7) + (s << 1)) = val;
            }
        }
    }
}

// ---- rescore + output epilogue: one wave per token; exact dot, norms from
// ---- precomputed f32 norm_sq (one uniform scalar load per candidate) ------
__global__ __launch_bounds__(256) void rescore_epilogue(
    const float* __restrict__ z, const float* __restrict__ emb,
    const unsigned int* __restrict__ cand, const float* __restrict__ norm_sq,
    float* __restrict__ out, float* __restrict__ loss_tok)
{
    int t = blockIdx.x * 4 + (threadIdx.x >> 6);   // global token (b,f,n)
    int lane = threadIdx.x & 63;
    int n = t & 255;
    int f = (t >> 8) & 1;
    int b = t >> 9;
    const float* zrow = z + ((size_t)(b*NN + n))*EDIM + f*CC;
    float4 za = *(const float4*)(zrow + lane * 8);
    float4 zb = *(const float4*)(zrow + lane * 8 + 4);

    // 128 candidates: lane reads slot s == lane (2 packed u32)
    uint2 cc = *(const uint2*)(cand + ((size_t)t << 7) + (lane << 1));
    unsigned c1 = cc.x, c2 = cc.y;

    unsigned m1 = (c1 > c2) ? c1 : c2;
    #pragma unroll
    for (int off = 32; off; off >>= 1) {
        unsigned o = __shfl_xor(m1, off);
        if (o > m1) m1 = o;
    }
    float thr = unford(m1) - MARGIN;

    unsigned long long bestp = 0ull;
    #pragma unroll
    for (int rnd = 0; rnd < 2; ++rnd) {
        unsigned u = rnd ? c2 : c1;
        float v = unford(u);
        unsigned long long mask = __ballot(v > thr);
        while (mask) {
            int src = __ffsll((long long)mask) - 1;
            mask &= mask - 1;
            unsigned cu = __shfl(u, src);
            int idx = (src << 6) | ((int)(cu & 63u) ^ 63);   // proto index [0,4096)
            const float* er = emb + ((size_t)(f * NE + idx)) * CC;
            float4 ea = *(const float4*)(er + lane * 8);
            float4 eb = *(const float4*)(er + lane * 8 + 4);
            float d  = za.x*ea.x + za.y*ea.y + za.z*ea.z + za.w*ea.w
                     + zb.x*eb.x + zb.y*eb.y + zb.z*eb.z + zb.w*eb.w;
            #pragma unroll
            for (int off = 32; off; off >>= 1) d += __shfl_xor(d, off);
            float se = norm_sq[f * NE + idx];                // exact f32 row norm^2
            float vex = d / fmaxf(sqrtf(se), 1e-12f);        // exact score
            unsigned long long pex = ((unsigned long long)ford(vex) << 32)
                                   | (unsigned int)(~(unsigned int)idx);
            if (pex > bestp) bestp = pex;
        }
    }
    int idxb = (int)(~(unsigned int)bestp);    // exact argmax (tie -> lower idx)

    // ---- output: z_q gather (codebook-0 row, faithful quirk) + loss -------
    // norm of the gathered GLOBAL row idxb (in [0,4096)) == norm_sq[idxb]
    const float* er0 = emb + (size_t)idxb * CC;
    float4 ea = *(const float4*)(er0 + lane * 8);
    float4 eb = *(const float4*)(er0 + lane * 8 + 4);
    float inm0 = 1.0f / fmaxf(sqrtf(norm_sq[idxb]), 1e-12f);
    float* orow = out + ((size_t)(b*NN + n))*EDIM + f*CC;
    ea.x *= inm0; ea.y *= inm0; ea.z *= inm0; ea.w *= inm0;
    eb.x *= inm0; eb.y *= inm0; eb.z *= inm0; eb.w *= inm0;
    *(float4*)(orow + lane * 8) = ea;
    *(float4*)(orow + lane * 8 + 4) = eb;
    float s1 = za.x*za.x + za.y*za.y + za.z*za.z + za.w*za.w
             + zb.x*zb.x + zb.y*zb.y + zb.z*zb.z + zb.w*zb.w;
    float s2 = za.x*ea.x + za.y*ea.y + za.z*ea.z + za.w*ea.w
             + zb.x*eb.x + zb.y*eb.y + zb.z*eb.z + zb.w*eb.w;
    #pragma unroll
    for (int off = 32; off; off >>= 1) {
        s1 += __shfl_xor(s1, off);
        s2 += __shfl_xor(s2, off);
    }
    if (lane == 0) {
        float cosv = s2 / fmaxf(sqrtf(s1), 1e-12f);   // zn . z_q (z_q already unit)
        loss_tok[t] = 2.0f - 2.0f * cosv;
        out[OUT_IDX + t] = (float)idxb;               // indices read back as float
    }
}

// ---- final: sum per-token losses -> out[OUT_LOSS] --------------------------
__global__ __launch_bounds__(256) void loss_reduce(
    const float* __restrict__ loss_tok, float* __restrict__ out)
{
    int tid = threadIdx.x;
    float s = 0.f;
    #pragma unroll
    for (int h = 0; h < 32; ++h) s += loss_tok[h * 256 + tid];
    #pragma unroll
    for (int off = 32; off; off >>= 1) s += __shfl_down(s, off);
    __shared__ float part[4];
    if ((tid & 63) == 0) part[tid >> 6] = s;
    __syncthreads();
    if (tid == 0) {
        float t = part[0] + part[1] + part[2] + part[3];
        out[OUT_LOSS] = t * (1.25f / (float)OUT_LOSS);
    }
}

extern "C" void kernel_launch(void* const* d_in, const int* in_sizes, int n_in,
                              void* d_out, int out_size, void* d_ws, size_t ws_size,
                              hipStream_t stream) {
    const float* z   = (const float*)d_in[0];
    const float* emb = (const float*)d_in[1];
    float* out = (float*)d_out;

    char* ws = (char*)d_ws;
    float* norm_sq = (float*)ws;                                    // 32 KB
    unsigned int* cand = (unsigned int*)(ws + 32768);               // 4 MB
    float* loss_tok = (float*)(ws + 32768 + (size_t)4*1024*1024);   // 32 KB
    short* z_hi = (short*)(ws + 65536 + (size_t)4*1024*1024);       // 8 MB
    short* e_hi = z_hi + (size_t)FCB * NE * CC;                     // 8 MB
    // ws needed: ~20.1 MB

    pack_hi<<<1024, 512, 0, stream>>>(z, emb, z_hi, e_hi, norm_sq);
    gemm_sel<<<dim3(NE/128, 4096/256, FCB), 512, 0, stream>>>(z_hi, e_hi, norm_sq, cand);
    rescore_epilogue<<<TOKENS/4, 256, 0, stream>>>(z, emb, cand, norm_sq, out, loss_tok);
    loss_reduce<<<1, 256, 0, stream>>>(loss_tok, out);
}

// Round 9
// 140.601 us; speedup vs baseline: 1.9948x; 1.9948x over previous
//
#include <hip/hip_runtime.h>
#include <hip/hip_bf16.h>
#include <stdint.h>

// Problem constants (fixed by setup_inputs)
#define FCB 2            // codebooks
#define BB 16            // batch
#define NN 256           // tokens per (b)
#define EDIM 1024
#define CC 512           // channels per codebook
#define NE 4096          // prototypes per codebook
#define TOKENS (BB*FCB*NN)   // 8192
#define ROWS (FCB*NE)        // 8192 emb rows
#define OUT_LOSS (BB*NN*EDIM)   // 4194304 (also the element count for the mean)
#define OUT_IDX  (OUT_LOSS + 1)
#define MARGIN 0.15f     // rescore margin, v-units (v = z.e/||e|| ~ 22.6*cos); ~24 sigma of bf16 noise

typedef __attribute__((ext_vector_type(8))) short bf16x8;   // MFMA A/B frag (4 VGPRs)
typedef __attribute__((ext_vector_type(4))) float f32x4;    // 16x16 MFMA C/D frag

// monotonic float<->uint mapping for packed argmax
__device__ __forceinline__ unsigned int ford(float v) {
    unsigned int u = __float_as_uint(v);
    return (u & 0x80000000u) ? ~u : (u | 0x80000000u);
}
__device__ __forceinline__ float unford(unsigned int u) {
    unsigned int b = (u & 0x80000000u) ? (u & 0x7fffffffu) : ~u;
    return __uint_as_float(b);
}

// ---------------------------------------------------------------------------
// ws layout:
//   [0]        norm_sq   8192 f32                   (32 KB)  written once by pack_hi (no atomics)
//   [32768]    cand      8192 tok x 64 slots x 2 u32 (4 MB)  top-2 per 64-col group
//   [32768+4M] loss_tok  8192 f32                   (32 KB)
//   [+32KB]    z_hi      2*4096*512 bf16            (8 MB)   fragment-packed
//   [+8MB]     e_hi      2*4096*512 bf16            (8 MB)
// Packed layout: elem = ((f*256 + R)*64 + Q)*128 + m*8 + j
//   (R = 16-row tile, Q = 8-elem k-chunk, m = row-in-tile, j = elem).
//   One 1-KB staging chunk = (R, qb..qb+3) = 16 rows x 32 k; both the
//   global_load_lds staging and ds_read_b128 fragment reads are lane-linear
//   (lane <-> 16 B), conflict-free.
//
// Session ledger (what's proven on this problem):
//   gemm: duration fits dur ~= 30 + 64/(blocks-per-CU concurrency) us.
//         R8's 256x128 8-wave tile spilled acc (launch_bounds(512,6) -> 85
//         VGPR cap < 116 needed; VGPR_Count=40, 330 MB scratch writes).
//         This round: SAME tile, bounds (512,4) = 128-VGPR budget, 2 blk/CU.
//         XCD remap (R4): 3x FETCH, no change -> NOT delivery-BW-bound.
//         Pointer hoist (R5): +16 VGPR, lost 3us at 128x128.
//   cross-block serialization (single-address atomic R2, threadfence+counter
//         R6) costs 60-70us.  Keep loss_reduce as its own 3us kernel.
// ---------------------------------------------------------------------------

// ---- pack: fp32 -> bf16 hi, fragment-packed.  512-thread blocks, 1024 total.
// z half (blocks 0..511): 8 token rows via LDS transpose -> coalesced fp32
//   reads AND lane-linear packed stores (single ds_write_b64 per 4 elems).
// emb half (blocks 512..1023): block owns a full (f,R) 16-row tile (512 k),
//   per-row exact f32 norm^2 reduced in-block, plain store (no atomics).
__global__ __launch_bounds__(512) void pack_hi(
    const float* __restrict__ z, const float* __restrict__ emb,
    short* __restrict__ z_hi, short* __restrict__ e_hi,
    float* __restrict__ norm_sq)
{
    int bid = blockIdx.x;
    int tid = threadIdx.x;
    if (bid < 512) {
        // ---- z: 8 rows x 1024 cols, LDS-transposed ----
        __shared__ short lds[8][1032];              // 2064B rows: 16B-aligned
        int row0 = bid * 8;                         // token row base
        #pragma unroll
        for (int it = 0; it < 4; ++it) {
            int flat = it * 512 + tid;              // [0,2048) float4 units
            int row = flat >> 8;                    // 256 float4 per row
            int col4 = flat & 255;
            float4 v = *(const float4*)(z + ((size_t)(row0 + row)) * EDIM + col4 * 4);
            unsigned short s0, s1, s2, s3;
            { __hip_bfloat16 h = __float2bfloat16(v.x); s0 = *(unsigned short*)&h; }
            { __hip_bfloat16 h = __float2bfloat16(v.y); s1 = *(unsigned short*)&h; }
            { __hip_bfloat16 h = __float2bfloat16(v.z); s2 = *(unsigned short*)&h; }
            { __hip_bfloat16 h = __float2bfloat16(v.w); s3 = *(unsigned short*)&h; }
            uint2 pk;
            pk.x = (unsigned)s0 | ((unsigned)s1 << 16);
            pk.y = (unsigned)s2 | ((unsigned)s3 << 16);
            *(uint2*)&lds[row][col4 * 4] = pk;      // one ds_write_b64
        }
        __syncthreads();
        int R = bid >> 1, mb = (bid & 1) * 8;       // 16-row group, m base
        int ml = tid & 7;
        int Q  = tid >> 3;                          // [0,64)
        #pragma unroll
        for (int f = 0; f < 2; ++f) {
            bf16x8 h8 = *(const bf16x8*)&lds[ml][f * 512 + Q * 8];
            size_t u = ((size_t)((f * 256 + R) * 64 + Q)) * 16 + mb + ml;
            *(bf16x8*)(z_hi + u * 8) = h8;          // lane-linear 16 B stores
        }
    } else {
        // ---- emb: block owns (f, R): 16 rows x 512 k; 2 chunk-units/thread
        __shared__ float red[512];
        int e = bid - 512;                          // [0,512)
        int f = e >> 8, R = e & 255;
        int m = tid & 15;                           // same row for both units
        float ss = 0.f;
        #pragma unroll
        for (int i = 0; i < 2; ++i) {
            int ul = tid + 512 * i;                 // [0,1024)
            int Q = (ul >> 4) & 63;
            const float* s = emb + ((size_t)(f * NE + R * 16 + m)) * CC + Q * 8;
            float4 v0 = *(const float4*)s;
            float4 v1 = *(const float4*)(s + 4);
            float vv[8] = {v0.x, v0.y, v0.z, v0.w, v1.x, v1.y, v1.z, v1.w};
            bf16x8 h8;
            #pragma unroll
            for (int j = 0; j < 8; ++j) {
                __hip_bfloat16 hb = __float2bfloat16(vv[j]);
                h8[j] = *(short*)&hb;
                ss = fmaf(vv[j], vv[j], ss);
            }
            int u = ((f * 256 + R) * 64 + Q) * 16 + m;
            *(bf16x8*)(e_hi + (size_t)u * 8) = h8;
        }
        red[tid] = ss;
        __syncthreads();
        if (tid < 16) {
            float t = 0.f;
            #pragma unroll
            for (int q = 0; q < 32; ++q) t += red[tid + 16 * q];
            norm_sq[f * NE + R * 16 + tid] = t;     // exact f32, no atomic
        }
    }
}

// ---------------------------------------------------------------------------
// 256x128 bf16 MFMA GEMM (BK=64) + top-2 select -- R0's proven 2-barrier
// schedule, widened to 8 waves (4M x 2N; wave = 64x64 = acc[4][4], same
// per-wave footprint as R0).  __launch_bounds__(512,4): 128-VGPR budget (the
// kernel needs ~116; R8's (512,6)=85 cap spilled acc to scratch).  48 KB LDS,
// 2 blocks/CU = 16 waves/CU vs R0's ~10.6; per-CU sequential step-slots
// halve (4 blocks x 8 steps vs 8 x 8); staged traffic 512 -> 384 MB.
// ---------------------------------------------------------------------------
__global__ __launch_bounds__(512, 4) void gemm_sel(
    const short* __restrict__ zh, const short* __restrict__ eh,
    const float* __restrict__ norm_sq, unsigned int* __restrict__ cand)
{
    __shared__ char smem[49152];      // A 32K (chunks 0..31) | B 16K (32..47)
    const int f  = blockIdx.z;
    const int t0 = blockIdx.y * 256;  // token base within codebook
    const int m0 = blockIdx.x * 128;  // proto base within codebook
    const int tid  = threadIdx.x;
    const int wave = tid >> 6, lane = tid & 63;
    const int wm = wave & 3, wn = wave >> 2;   // 4 M-waves x 2 N-waves

    f32x4 acc[4][4] = {};

    for (int step = 0; step < 8; ++step) {
        __syncthreads();              // previous compute done before overwrite
        // 48 chunks of 1 KB per step: A (c<32), B (c>=32); wave stages 6
        #pragma unroll
        for (int i = 0; i < 6; ++i) {
            int c = wave * 6 + i;
            bool isA = (c < 32);
            const short* gsrc = isA ? zh : eh;
            int cl = isA ? c : (c - 32);
            int Rl = cl >> 1, h = cl & 1;
            int R = (isA ? (t0 >> 4) : (m0 >> 4)) + Rl;
            int qb = step * 8 + h * 4;
            const short* g = gsrc
                + (((size_t)f * 256 + R) * 64 + qb) * 128 + (size_t)lane * 8;
            __builtin_amdgcn_global_load_lds(
                (const __attribute__((address_space(1))) void*)g,
                (__attribute__((address_space(3))) void*)(smem + c * 1024),
                16, 0, 0);
        }
        __syncthreads();              // staged data visible to all waves

        #pragma unroll
        for (int h = 0; h < 2; ++h) {
            bf16x8 ah[4], bh[4];
            #pragma unroll
            for (int i = 0; i < 4; ++i) {
                ah[i] = *(const bf16x8*)(smem + ((wm*4 + i)*2 + h) * 1024 + lane * 16);
                bh[i] = *(const bf16x8*)(smem + 32768 + ((wn*4 + i)*2 + h) * 1024 + lane * 16);
            }
            #pragma unroll
            for (int i = 0; i < 4; ++i)
                #pragma unroll
                for (int j2 = 0; j2 < 4; ++j2)
                    acc[i][j2] = __builtin_amdgcn_mfma_f32_16x16x32_bf16(ah[i], bh[j2], acc[i][j2], 0, 0, 0);
        }
    }

    // ---- selection epilogue: per token, top-2 over this wave's 64 cols ----
    // C/D layout (16x16x32): col = lane&15, row = (lane>>4)*4 + reg
    // u32 pack: score high bits | (col_local ^ 63)  (tie -> lower col wins;
    // truncation error <= 2e-4 absorbed by MARGIN; exact rescore follows)
    float inm[4]; unsigned ccode[4];
    #pragma unroll
    for (int j2 = 0; j2 < 4; ++j2) {
        int col = j2 * 16 + (lane & 15);              // [0,64) within wave group
        ccode[j2] = (unsigned)(col ^ 63);
        inm[j2] = rsqrtf(norm_sq[f * NE + m0 + wn * 64 + col]);
    }

    #pragma unroll
    for (int i = 0; i < 4; ++i) {
        #pragma unroll
        for (int r = 0; r < 4; ++r) {
            unsigned p1 = 0u, p2 = 0u;
            #pragma unroll
            for (int j2 = 0; j2 < 4; ++j2) {
                float w = acc[i][j2][r] * inm[j2];
                unsigned pw = (ford(w) & 0xFFFFFFC0u) | ccode[j2];
                if (pw > p1) { p2 = p1; p1 = pw; }
                else if (pw > p2) p2 = pw;
            }
            // merge top-2 across the 16 contiguous lanes of this token row
            #pragma unroll
            for (int off = 8; off; off >>= 1) {
                unsigned q1 = __shfl_down(p1, off, 16);
                unsigned q2 = __shfl_down(p2, off, 16);
                if (q1 > p1) { unsigned t = p1; p1 = q1; p2 = (t > q2) ? t : q2; }
                else         { p2 = (p2 > q1) ? p2 : q1; }
            }
            if ((lane & 15) == 0) {
                int u = t0 + wm * 64 + i * 16 + (lane >> 4) * 4 + r;
                int b = u >> 8, n = u & 255;
                int gt = ((b * FCB + f) << 8) + n;   // global token id (b,f,n)
                int s = (blockIdx.x << 1) | wn;      // slot covers cols s*64..
                uint2 val; val.x = p1; val.y = p2;
                *(uint2*)(cand + ((size_t)gt << 7) + (s << 1)) = val;
            }
        }
    }
}

// ---- rescore + output epilogue: one wave per token; exact dot, norms from
// ---- precomputed f32 norm_sq (one uniform scalar load per candidate) ------
__global__ __launch_bounds__(256) void rescore_epilogue(
    const float* __restrict__ z, const float* __restrict__ emb,
    const unsigned int* __restrict__ cand, const float* __restrict__ norm_sq,
    float* __restrict__ out, float* __restrict__ loss_tok)
{
    int t = blockIdx.x * 4 + (threadIdx.x >> 6);   // global token (b,f,n)
    int lane = threadIdx.x & 63;
    int n = t & 255;
    int f = (t >> 8) & 1;
    int b = t >> 9;
    const float* zrow = z + ((size_t)(b*NN + n))*EDIM + f*CC;
    float4 za = *(const float4*)(zrow + lane * 8);
    float4 zb = *(const float4*)(zrow + lane * 8 + 4);

    // 128 candidates: lane reads slot s == lane (2 packed u32)
    uint2 cc = *(const uint2*)(cand + ((size_t)t << 7) + (lane << 1));
    unsigned c1 = cc.x, c2 = cc.y;

    unsigned m1 = (c1 > c2) ? c1 : c2;
    #pragma unroll
    for (int off = 32; off; off >>= 1) {
        unsigned o = __shfl_xor(m1, off);
        if (o > m1) m1 = o;
    }
    float thr = unford(m1) - MARGIN;

    unsigned long long bestp = 0ull;
    #pragma unroll
    for (int rnd = 0; rnd < 2; ++rnd) {
        unsigned u = rnd ? c2 : c1;
        float v = unford(u);
        unsigned long long mask = __ballot(v > thr);
        while (mask) {
            int src = __ffsll((long long)mask) - 1;
            mask &= mask - 1;
            unsigned cu = __shfl(u, src);
            int idx = (src << 6) | ((int)(cu & 63u) ^ 63);   // proto index [0,4096)
            const float* er = emb + ((size_t)(f * NE + idx)) * CC;
            float4 ea = *(const float4*)(er + lane * 8);
            float4 eb = *(const float4*)(er + lane * 8 + 4);
            float d  = za.x*ea.x + za.y*ea.y + za.z*ea.z + za.w*ea.w
                     + zb.x*eb.x + zb.y*eb.y + zb.z*eb.z + zb.w*eb.w;
            #pragma unroll
            for (int off = 32; off; off >>= 1) d += __shfl_xor(d, off);
            float se = norm_sq[f * NE + idx];                // exact f32 row norm^2
            float vex = d / fmaxf(sqrtf(se), 1e-12f);        // exact score
            unsigned long long pex = ((unsigned long long)ford(vex) << 32)
                                   | (unsigned int)(~(unsigned int)idx);
            if (pex > bestp) bestp = pex;
        }
    }
    int idxb = (int)(~(unsigned int)bestp);    // exact argmax (tie -> lower idx)

    // ---- output: z_q gather (codebook-0 row, faithful quirk) + loss -------
    // norm of the gathered GLOBAL row idxb (in [0,4096)) == norm_sq[idxb]
    const float* er0 = emb + (size_t)idxb * CC;
    float4 ea = *(const float4*)(er0 + lane * 8);
    float4 eb = *(const float4*)(er0 + lane * 8 + 4);
    float inm0 = 1.0f / fmaxf(sqrtf(norm_sq[idxb]), 1e-12f);
    float* orow = out + ((size_t)(b*NN + n))*EDIM + f*CC;
    ea.x *= inm0; ea.y *= inm0; ea.z *= inm0; ea.w *= inm0;
    eb.x *= inm0; eb.y *= inm0; eb.z *= inm0; eb.w *= inm0;
    *(float4*)(orow + lane * 8) = ea;
    *(float4*)(orow + lane * 8 + 4) = eb;
    float s1 = za.x*za.x + za.y*za.y + za.z*za.z + za.w*za.w
             + zb.x*zb.x + zb.y*zb.y + zb.z*zb.z + zb.w*zb.w;
    float s2 = za.x*ea.x + za.y*ea.y + za.z*ea.z + za.w*ea.w
             + zb.x*eb.x + zb.y*eb.y + zb.z*eb.z + zb.w*eb.w;
    #pragma unroll
    for (int off = 32; off; off >>= 1) {
        s1 += __shfl_xor(s1, off);
        s2 += __shfl_xor(s2, off);
    }
    if (lane == 0) {
        float cosv = s2 / fmaxf(sqrtf(s1), 1e-12f);   // zn . z_q (z_q already unit)
        loss_tok[t] = 2.0f - 2.0f * cosv;
        out[OUT_IDX + t] = (float)idxb;               // indices read back as float
    }
}

// ---- final: sum per-token losses -> out[OUT_LOSS] --------------------------
__global__ __launch_bounds__(256) void loss_reduce(
    const float* __restrict__ loss_tok, float* __restrict__ out)
{
    int tid = threadIdx.x;
    float s = 0.f;
    #pragma unroll
    for (int h = 0; h < 32; ++h) s += loss_tok[h * 256 + tid];
    #pragma unroll
    for (int off = 32; off; off >>= 1) s += __shfl_down(s, off);
    __shared__ float part[4];
    if ((tid & 63) == 0) part[tid >> 6] = s;
    __syncthreads();
    if (tid == 0) {
        float t = part[0] + part[1] + part[2] + part[3];
        out[OUT_LOSS] = t * (1.25f / (float)OUT_LOSS);
    }
}

extern "C" void kernel_launch(void* const* d_in, const int* in_sizes, int n_in,
                              void* d_out, int out_size, void* d_ws, size_t ws_size,
                              hipStream_t stream) {
    const float* z   = (const float*)d_in[0];
    const float* emb = (const float*)d_in[1];
    float* out = (float*)d_out;

    char* ws = (char*)d_ws;
    float* norm_sq = (float*)ws;                                    // 32 KB
    unsigned int* cand = (unsigned int*)(ws + 32768);               // 4 MB
    float* loss_tok = (float*)(ws + 32768 + (size_t)4*1024*1024);   // 32 KB
    short* z_hi = (short*)(ws + 65536 + (size_t)4*1024*1024);       // 8 MB
    short* e_hi = z_hi + (size_t)FCB * NE * CC;                     // 8 MB
    // ws needed: ~20.1 MB

    pack_hi<<<1024, 512, 0, stream>>>(z, emb, z_hi, e_hi, norm_sq);
    gemm_sel<<<dim3(NE/128, 4096/256, FCB), 512, 0, stream>>>(z_hi, e_hi, norm_sq, cand);
    rescore_epilogue<<<TOKENS/4, 256, 0, stream>>>(z, emb, cand, norm_sq, out, loss_tok);
    loss_reduce<<<1, 256, 0, stream>>>(loss_tok, out);
}